// Round 1
// baseline (99.664 us; speedup 1.0000x reference)
//
#include <hip/hip_runtime.h>
#include <math.h>

// Problem constants (fixed by setup_inputs)
constexpr int kB = 16, kN = 900, kC = 92, kT = 960;
constexpr int kBN = kB * kN;          // 14400 rows
constexpr int ROWS = 4;               // rows per block (one wave each for softmax)
constexpr int THREADS = 256;

__global__ __launch_bounds__(THREADS) void matcher_kernel(
    const float* __restrict__ out_labels,   // [BN, C]
    const float* __restrict__ out_bboxes,   // [BN, 4] cxcywh
    const int*   __restrict__ tgt_labels,   // [T]
    const float* __restrict__ tgt_bboxes,   // [T, 4] used as-is (xyxy per reference NOTE)
    float*       __restrict__ cost)         // [BN, T]
{
    __shared__ float4 s_tb[kT];             // 15360 B
    __shared__ int    s_lab[kT];            // 3840 B
    __shared__ float  s_probs[ROWS][kC];    // 1472 B
    __shared__ float  s_row[ROWS][12];      // row-derived: cx,cy,w,h,x0,y0,x1,y1,area1

    const int tid  = threadIdx.x;
    const int row0 = blockIdx.x * ROWS;

    // Stage target data into LDS (coalesced float4 / int loads)
    const float4* tb4 = (const float4*)tgt_bboxes;
    for (int i = tid; i < kT; i += THREADS) {
        s_tb[i]  = tb4[i];
        s_lab[i] = tgt_labels[i];
    }

    // Per-row softmax: wave w handles row w (C=92 -> lanes cover [0,64) and [64,92))
    {
        const int wave = tid >> 6;
        const int lane = tid & 63;
        const int r = wave;
        const int p = row0 + r;
        const float* lrow = out_labels + (size_t)p * kC;
        float x0 = (lane < kC)      ? lrow[lane]      : -INFINITY;
        float x1 = (lane + 64 < kC) ? lrow[lane + 64] : -INFINITY;
        float m = fmaxf(x0, x1);
        #pragma unroll
        for (int off = 32; off > 0; off >>= 1)
            m = fmaxf(m, __shfl_down(m, off, 64));
        m = __shfl(m, 0, 64);
        float e0 = (lane < kC)      ? expf(x0 - m) : 0.0f;
        float e1 = (lane + 64 < kC) ? expf(x1 - m) : 0.0f;
        float s = e0 + e1;
        #pragma unroll
        for (int off = 32; off > 0; off >>= 1)
            s += __shfl_down(s, off, 64);
        s = __shfl(s, 0, 64);
        float inv = 1.0f / s;
        if (lane < kC)      s_probs[r][lane]      = e0 * inv;
        if (lane + 64 < kC) s_probs[r][lane + 64] = e1 * inv;
        if (lane == 0) {
            float4 bb = ((const float4*)out_bboxes)[p];
            float hw = 0.5f * bb.z, hh = 0.5f * bb.w;
            float bx0 = bb.x - hw, by0 = bb.y - hh;
            float bx1 = bb.x + hw, by1 = bb.y + hh;
            s_row[r][0] = bb.x; s_row[r][1] = bb.y;
            s_row[r][2] = bb.z; s_row[r][3] = bb.w;
            s_row[r][4] = bx0;  s_row[r][5] = by0;
            s_row[r][6] = bx1;  s_row[r][7] = by1;
            s_row[r][8] = (bx1 - bx0) * (by1 - by0);   // area1, same order as ref
        }
    }
    __syncthreads();

    // Pairwise cost: per row, thread-stride over T (coalesced stores)
    for (int r = 0; r < ROWS; ++r) {
        const int p = row0 + r;
        const float cx = s_row[r][0], cy = s_row[r][1];
        const float w  = s_row[r][2], h  = s_row[r][3];
        const float bx0 = s_row[r][4], by0 = s_row[r][5];
        const float bx1 = s_row[r][6], by1 = s_row[r][7];
        const float area1 = s_row[r][8];
        float* orow = cost + (size_t)p * kT;
        for (int t = tid; t < kT; t += THREADS) {
            float4 tb = s_tb[t];
            // L1 on raw cxcywh vs target (torch.cdist p=1 semantics)
            float l1 = fabsf(cx - tb.x) + fabsf(cy - tb.y)
                     + fabsf(w  - tb.z) + fabsf(h  - tb.w);
            // GIoU: pred converted to xyxy, target used as-is
            float ltx = fmaxf(bx0, tb.x), lty = fmaxf(by0, tb.y);
            float rbx = fminf(bx1, tb.z), rby = fminf(by1, tb.w);
            float iw = fmaxf(rbx - ltx, 0.0f), ih = fmaxf(rby - lty, 0.0f);
            float inter = iw * ih;
            float area2 = (tb.z - tb.x) * (tb.w - tb.y);
            float uni = area1 + area2 - inter;
            float iou = inter / uni;
            float ex0 = fminf(bx0, tb.x), ey0 = fminf(by0, tb.y);
            float ex1 = fmaxf(bx1, tb.z), ey1 = fmaxf(by1, tb.w);
            float ew = fmaxf(ex1 - ex0, 0.0f), eh = fmaxf(ey1 - ey0, 0.0f);
            float area_e = ew * eh;
            float giou = iou - (area_e - uni) / area_e;
            float cl = 1.0f - s_probs[r][s_lab[t]];
            orow[t] = cl + 5.0f * l1 + 2.0f * (1.0f - giou);
        }
    }
}

extern "C" void kernel_launch(void* const* d_in, const int* in_sizes, int n_in,
                              void* d_out, int out_size, void* d_ws, size_t ws_size,
                              hipStream_t stream) {
    const float* out_labels = (const float*)d_in[0];
    const float* out_bboxes = (const float*)d_in[1];
    const int*   tgt_labels = (const int*)d_in[2];
    const float* tgt_bboxes = (const float*)d_in[3];
    float* cost = (float*)d_out;
    dim3 grid(kBN / ROWS);   // 14400/4 = 3600 blocks
    matcher_kernel<<<grid, THREADS, 0, stream>>>(out_labels, out_bboxes,
                                                 tgt_labels, tgt_bboxes, cost);
}

// Round 2
// 91.573 us; speedup vs baseline: 1.0884x; 1.0884x over previous
//
#include <hip/hip_runtime.h>
#include <math.h>

// Problem constants (fixed by setup_inputs)
constexpr int kB = 16, kN = 900, kC = 92, kT = 960;
constexpr int kBN = kB * kN;          // 14400 rows
constexpr int ROWS = 4;               // rows per block (one wave each for softmax)
constexpr int THREADS = 256;

__global__ __launch_bounds__(THREADS) void matcher_kernel(
    const float* __restrict__ out_labels,   // [BN, C]
    const float* __restrict__ out_bboxes,   // [BN, 4] cxcywh
    const int*   __restrict__ tgt_labels,   // [T]
    const float* __restrict__ tgt_bboxes,   // [T, 4] used as-is (xyxy per reference NOTE)
    float*       __restrict__ cost)         // [BN, T]
{
    __shared__ float4 s_tb[kT];             // 15360 B
    __shared__ int    s_lab[kT];            // 3840 B
    __shared__ float  s_cl[ROWS][kC];       // 5 - prob  (class-cost table)
    __shared__ float4 s_rowA[ROWS];         // cx,cy,w,h
    __shared__ float4 s_rowB[ROWS];         // bx0,by0,bx1,by1
    __shared__ float  s_rowC[ROWS];         // area1

    const int tid  = threadIdx.x;
    const int row0 = blockIdx.x * ROWS;

    // Stage target data into LDS (coalesced float4 / int loads)
    const float4* tb4 = (const float4*)tgt_bboxes;
    for (int i = tid; i < kT; i += THREADS) {
        s_tb[i]  = tb4[i];
        s_lab[i] = tgt_labels[i];
    }

    // Per-row softmax: wave w handles row w (C=92 -> lanes cover [0,64) and [64,92))
    {
        const int r = tid >> 6;
        const int lane = tid & 63;
        const int p = row0 + r;
        const float* lrow = out_labels + (size_t)p * kC;
        float x0 = (lane < kC)      ? lrow[lane]      : -INFINITY;
        float x1 = (lane + 64 < kC) ? lrow[lane + 64] : -INFINITY;
        float m = fmaxf(x0, x1);
        #pragma unroll
        for (int off = 32; off > 0; off >>= 1)
            m = fmaxf(m, __shfl_down(m, off, 64));
        m = __shfl(m, 0, 64);
        float e0 = (lane < kC)      ? expf(x0 - m) : 0.0f;
        float e1 = (lane + 64 < kC) ? expf(x1 - m) : 0.0f;
        float s = e0 + e1;
        #pragma unroll
        for (int off = 32; off > 0; off >>= 1)
            s += __shfl_down(s, off, 64);
        s = __shfl(s, 0, 64);
        float inv = 1.0f / s;
        // store 5 - prob: folds the "+4" GIoU/label constant into the gather value
        if (lane < kC)      s_cl[r][lane]      = 5.0f - e0 * inv;
        if (lane + 64 < kC) s_cl[r][lane + 64] = 5.0f - e1 * inv;
        if (lane == 0) {
            float4 bb = ((const float4*)out_bboxes)[p];
            float hw = 0.5f * bb.z, hh = 0.5f * bb.w;
            float bx0 = bb.x - hw, by0 = bb.y - hh;
            float bx1 = bb.x + hw, by1 = bb.y + hh;
            s_rowA[r] = bb;
            s_rowB[r] = make_float4(bx0, by0, bx1, by1);
            s_rowC[r] = (bx1 - bx0) * (by1 - by0);   // area1, same order as ref
        }
    }
    __syncthreads();

    // Pair phase: each thread owns 4 consecutive targets (t0..t0+3), loops rows.
    const int t0 = tid * 4;
    if (t0 < kT) {
        // Hoist per-target data into registers (reused across all 4 rows)
        float4 tb[4]; float a2[4]; int li[4];
        #pragma unroll
        for (int i = 0; i < 4; ++i) {
            tb[i] = s_tb[t0 + i];
            a2[i] = (tb[i].z - tb[i].x) * (tb[i].w - tb[i].y);
            li[i] = s_lab[t0 + i];
        }
        #pragma unroll
        for (int r = 0; r < ROWS; ++r) {
            const int p = row0 + r;
            float4 ra = s_rowA[r];          // cx,cy,w,h   (LDS broadcast)
            float4 rb = s_rowB[r];          // bx0,by0,bx1,by1
            float area1 = s_rowC[r];
            float4 res;
            float* resp = &res.x;
            #pragma unroll
            for (int i = 0; i < 4; ++i) {
                float4 t = tb[i];
                // L1 on raw cxcywh vs target (torch.cdist p=1 semantics)
                float l1 = fabsf(ra.x - t.x) + fabsf(ra.y - t.y)
                         + fabsf(ra.z - t.z) + fabsf(ra.w - t.w);
                // intersection (clamp needed)
                float ltx = fmaxf(rb.x, t.x), lty = fmaxf(rb.y, t.y);
                float rbx = fminf(rb.z, t.z), rby = fminf(rb.w, t.w);
                float iw = fmaxf(rbx - ltx, 0.0f), ih = fmaxf(rby - lty, 0.0f);
                float inter = iw * ih;
                float uni = area1 + a2[i] - inter;
                // enclosing box (clamp is a no-op: pred w,h >= 0 ⇒ ex1>=ex0, ey1>=ey0)
                float ex0 = fminf(rb.x, t.x), ey0 = fminf(rb.y, t.y);
                float ex1 = fmaxf(rb.z, t.z), ey1 = fmaxf(rb.w, t.w);
                float area_e = (ex1 - ex0) * (ey1 - ey0);
                // cost = (5 - prob) + 5*L1 - 2*inter/uni - 2*uni/area_e
                float rcpu = __builtin_amdgcn_rcpf(uni);
                float rcpe = __builtin_amdgcn_rcpf(area_e);
                float v = s_cl[r][li[i]];
                v = fmaf(5.0f, l1, v);
                v = fmaf(-2.0f * inter, rcpu, v);
                v = fmaf(-2.0f * uni, rcpe, v);
                resp[i] = v;
            }
            ((float4*)(cost + (size_t)p * kT))[tid] = res;
        }
    }
}

extern "C" void kernel_launch(void* const* d_in, const int* in_sizes, int n_in,
                              void* d_out, int out_size, void* d_ws, size_t ws_size,
                              hipStream_t stream) {
    const float* out_labels = (const float*)d_in[0];
    const float* out_bboxes = (const float*)d_in[1];
    const int*   tgt_labels = (const int*)d_in[2];
    const float* tgt_bboxes = (const float*)d_in[3];
    float* cost = (float*)d_out;
    dim3 grid(kBN / ROWS);   // 14400/4 = 3600 blocks
    matcher_kernel<<<grid, THREADS, 0, stream>>>(out_labels, out_bboxes,
                                                 tgt_labels, tgt_bboxes, cost);
}